// Round 13
// baseline (224.285 us; speedup 1.0000x reference)
//
#include <hip/hip_runtime.h>

#define N_NODES   50000
#define N_EDGES   800000
#define DIM       128
#define N_GRAPHS  64
#define N_CLASSES 10
#define NCHE      128                  // edge chunks (u8-safe)
#define CSZ       (N_EDGES / NCHE)     // 6250
#define LQ        (N_NODES / 4)        // 12500 u8-packed words (4 nodes/word)
#define WPB       64                   // words per reduce block (256 nodes)
#define NBR2      ((LQ + WPB - 1) / WPB)   // 196
#define PLACE_BPC ((CSZ + 255) / 256)      // 25
#define PLACE_BLKS (NCHE * PLACE_BPC)      // 3200
#define PRES_BLKS ((N_NODES * DIM / 8 + 255) / 256)  // 3125
#define WT_BLKS   (DIM * DIM / 256)        // 64
#define NPBM      128                  // nodes per block in k_node (MFMA)
#define NBLK_NODE ((N_NODES + NPBM - 1) / NPBM)  // 391

typedef _Float16 h8 __attribute__((ext_vector_type(8)));
typedef float f4v __attribute__((ext_vector_type(4)));

// ---- per-chunk LDS histograms (u8 packed), dst/src phases in parallel blocks
__global__ __launch_bounds__(256) void k_lhist(const int* __restrict__ src,
                                               const int* __restrict__ dst,
                                               unsigned* __restrict__ Hin,
                                               unsigned* __restrict__ Hout,
                                               unsigned char* __restrict__ perm) {
    __shared__ unsigned L[LQ];         // 50 KB
    int c = blockIdx.x, t = threadIdx.x;
    int base = c * CSZ;
    for (int w = t; w < LQ; w += 256) L[w] = 0u;
    __syncthreads();
    if (blockIdx.y == 0) {
        for (int i = t; i < CSZ; i += 256) {
            int d = dst[base + i];
            int sh = (d & 3) * 8;
            unsigned old = atomicAdd(&L[d >> 2], 1u << sh);
            perm[base + i] = (unsigned char)((old >> sh) & 0xffu);
        }
        __syncthreads();
        for (int w = t; w < LQ; w += 256) Hin[(size_t)c * LQ + w] = L[w];
    } else {
        for (int i = t; i < CSZ; i += 256) {
            int s = src[base + i];
            atomicAdd(&L[s >> 2], 1u << ((s & 3) * 8));
        }
        __syncthreads();
        for (int w = t; w < LQ; w += 256) Hout[(size_t)c * LQ + w] = L[w];
    }
}

// ---- reduce: degrees/norms; Hin := per-chunk prefix; boundaries; scan p1 ----
__global__ __launch_bounds__(256) void k_reduce(unsigned* __restrict__ Hin,
                                                const unsigned* __restrict__ Hout,
                                                const int* __restrict__ gid,
                                                unsigned* __restrict__ indeg,
                                                float* __restrict__ outnorm,
                                                float* __restrict__ innorm,
                                                int* __restrict__ start,
                                                unsigned* __restrict__ row_ptr,
                                                unsigned* __restrict__ blockSums) {
    __shared__ unsigned sIn[4][WPB];
    __shared__ unsigned sOut[4][WPB];
    __shared__ unsigned sS[WPB];
    int t = threadIdx.x;
    int wl = t & (WPB - 1);
    int g  = t >> 6;
    int w  = blockIdx.x * WPB + wl;
    unsigned gs = 0, os = 0;
    int c0 = g * (NCHE / 4);
    if (w < LQ) {
        for (int c = c0; c < c0 + NCHE / 4; ++c) {
            gs += Hin[(size_t)c * LQ + w];
            os += Hout[(size_t)c * LQ + w];
        }
    }
    sIn[g][wl] = gs; sOut[g][wl] = os;
    __syncthreads();
    unsigned baseg = 0;
    for (int gg = 0; gg < 4; ++gg) if (gg < g) baseg += sIn[gg][wl];
    if (w < LQ) {
        unsigned running = baseg;
        for (int c = c0; c < c0 + NCHE / 4; ++c) {
            size_t idx = (size_t)c * LQ + w;
            unsigned word = Hin[idx];
            Hin[idx] = running;
            running += word;
        }
    }
    unsigned tot = 0, otot = 0, wtot = 0;
    if (t < WPB) {
        tot  = sIn[0][t] + sIn[1][t] + sIn[2][t] + sIn[3][t];
        otot = sOut[0][t] + sOut[1][t] + sOut[2][t] + sOut[3][t];
        wtot = (tot & 0xffu) + ((tot >> 8) & 0xffu) + ((tot >> 16) & 0xffu) + (tot >> 24);
        sS[t] = wtot;
    }
    __syncthreads();
    for (int off = 1; off < WPB; off <<= 1) {
        unsigned x = (t < WPB && t >= off) ? sS[t - off] : 0u;
        __syncthreads();
        if (t < WPB) sS[t] += x;
        __syncthreads();
    }
    if (t < WPB) {
        int ww = blockIdx.x * WPB + t;
        if (ww < LQ) {
            unsigned r0 = tot & 0xffu, r1 = (tot >> 8) & 0xffu,
                     r2 = (tot >> 16) & 0xffu, r3 = tot >> 24;
            unsigned o0 = otot & 0xffu, o1 = (otot >> 8) & 0xffu,
                     o2 = (otot >> 16) & 0xffu, o3 = otot >> 24;
            unsigned ex = sS[t] - wtot;
            int n = 4 * ww;
            row_ptr[n]     = ex;
            row_ptr[n + 1] = ex + r0;
            row_ptr[n + 2] = ex + r0 + r1;
            row_ptr[n + 3] = ex + r0 + r1 + r2;
            unsigned rr[4] = {r0, r1, r2, r3}, oo[4] = {o0, o1, o2, o3};
#pragma unroll
            for (int j = 0; j < 4; ++j) {
                indeg[n + j]   = rr[j];
                innorm[n + j]  = rsqrtf(fmaxf((float)rr[j], 1.0f));
                outnorm[n + j] = rsqrtf(fmaxf((float)oo[j], 1.0f));
                int i = n + j;
                int gq = gid[i];
                if (i == 0) {
                    for (int x2 = 0; x2 <= gq; ++x2) start[x2] = 0;
                } else {
                    int gp = gid[i - 1];
                    if (gp != gq)
                        for (int x2 = gp + 1; x2 <= gq; ++x2) start[x2] = i;
                }
                if (i == N_NODES - 1)
                    for (int x2 = gq + 1; x2 <= N_GRAPHS; ++x2) start[x2] = N_NODES;
            }
        }
        if (t == WPB - 1) blockSums[blockIdx.x] = sS[WPB - 1];
    }
}

// ---- scan pass 2 + pooled zeroing -------------------------------------------
__global__ __launch_bounds__(256) void k_scan2(unsigned* __restrict__ blockSums,
                                               unsigned* __restrict__ blockOff,
                                               float* __restrict__ pooled) {
    __shared__ unsigned s[256];
    int t = threadIdx.x;
    unsigned val = (t < NBR2) ? blockSums[t] : 0u;
    s[t] = val;
    __syncthreads();
    for (int off = 1; off < 256; off <<= 1) {
        unsigned x = (t >= off) ? s[t - off] : 0u;
        __syncthreads();
        s[t] += x;
        __syncthreads();
    }
    if (t < NBR2) blockOff[t] = s[t] - val;
    float4 z = {0.f, 0.f, 0.f, 0.f};
    for (int i = t; i < N_GRAPHS * DIM / 4; i += 256)
        reinterpret_cast<float4*>(pooled)[i] = z;
}

// ---- fused: CSR place + fp16 prescale (BLOCKED layout) + W^T fp16 build -----
// sfeat blocked: sfeat[(p*N + n)*32 + (d&31)], p = d>>5 — 3.2 MB per pass slice.
__global__ __launch_bounds__(256) void k_prep(const int* __restrict__ src,
                                              const int* __restrict__ dst,
                                              const unsigned* __restrict__ Hin,
                                              const unsigned char* __restrict__ perm,
                                              const unsigned* __restrict__ row_ptr,
                                              const unsigned* __restrict__ blockOff,
                                              int* __restrict__ bsrc,
                                              const float* __restrict__ feat,
                                              const float* __restrict__ outnorm,
                                              _Float16* __restrict__ sfeat,
                                              const float* __restrict__ W,
                                              _Float16* __restrict__ Wt) {
    int t = threadIdx.x;
    int blk = blockIdx.x;
    if (blk < PLACE_BLKS) {
        int c = blk / PLACE_BPC;
        int i = (blk % PLACE_BPC) * 256 + t;
        if (i < CSZ) {
            int e = c * CSZ + i;
            int d = dst[e];
            int sh = (d & 3) * 8;
            unsigned pre = (Hin[(size_t)c * LQ + (d >> 2)] >> sh) & 0xffu;
            unsigned pos = row_ptr[d] + blockOff[d >> 8] + pre + perm[e];
            bsrc[pos] = src[e];
        }
    } else if (blk < PLACE_BLKS + PRES_BLKS) {
        int i = (blk - PLACE_BLKS) * 256 + t;
        if (i < N_NODES * DIM / 8) {
            int n = i >> 4;
            int d = (i & 15) << 3;
            int p = d >> 5, off = d & 31;
            float nrm = outnorm[n];
            const float4* pp = reinterpret_cast<const float4*>(feat + (size_t)n * DIM + d);
            float4 a = pp[0], q = pp[1];
            h8 r;
            r[0] = (_Float16)(a.x * nrm); r[1] = (_Float16)(a.y * nrm);
            r[2] = (_Float16)(a.z * nrm); r[3] = (_Float16)(a.w * nrm);
            r[4] = (_Float16)(q.x * nrm); r[5] = (_Float16)(q.y * nrm);
            r[6] = (_Float16)(q.z * nrm); r[7] = (_Float16)(q.w * nrm);
            *reinterpret_cast<h8*>(sfeat + ((size_t)p * N_NODES + n) * 32 + off) = r;
        }
    } else {
        int i = (blk - PLACE_BLKS - PRES_BLKS) * 256 + t;  // i < DIM*DIM
        int n = i >> 7, k = i & 127;
        Wt[n * DIM + k] = (_Float16)W[k * DIM + n];
    }
}

#define CVT8(ACC_A, ACC_B, R, M) \
    ACC_A.x += (M) * (float)R[0]; ACC_A.y += (M) * (float)R[1]; \
    ACC_A.z += (M) * (float)R[2]; ACC_A.w += (M) * (float)R[3]; \
    ACC_B.x += (M) * (float)R[4]; ACC_B.y += (M) * (float)R[5]; \
    ACC_B.z += (M) * (float)R[6]; ACC_B.w += (M) * (float)R[7];

// ---- gather-sum, L2-BLOCKED: blockIdx.y = pass (32 dims, 3.2 MB slice) ------
// 4 lanes x 8 dims per edge row; 16 edge slots/wave, 2 rows in flight.
__global__ __launch_bounds__(256) void k_gather(const int* __restrict__ bsrc,
                                                const unsigned* __restrict__ row_ptr,
                                                const unsigned* __restrict__ blockOff,
                                                const unsigned* __restrict__ indeg,
                                                const _Float16* __restrict__ sfeat,
                                                const float* __restrict__ innorm,
                                                _Float16* __restrict__ aggh) {
    int tid = threadIdx.x;
    int wave = tid >> 6;
    int lane = tid & 63;
    int node = blockIdx.x * 4 + wave;
    if (node >= N_NODES) return;
    int p = blockIdx.y;
    const _Float16* sbase = sfeat + (size_t)p * N_NODES * 32;
    unsigned start = row_ptr[node] + blockOff[node >> 8];
    unsigned deg   = indeg[node];
    unsigned lim   = deg < 64u ? deg : 64u;
    int slot = lane >> 2;          // 0..15 edge slot
    int d8   = (lane & 3) << 3;    // dim base within 32-dim slice
    int sIdx = 0;
    if ((unsigned)lane < lim) sIdx = bsrc[start + lane];
    float4 accA = {0,0,0,0}, accB = {0,0,0,0};
    float4 accC = {0,0,0,0}, accD = {0,0,0,0};
    for (unsigned j = 0; j < lim; j += 32) {
        unsigned j0 = j + slot, j1 = j + 16 + slot;
        int s0 = __shfl(sIdx, (int)(j0 < lim ? j0 : 0u));
        int s1 = __shfl(sIdx, (int)(j1 < lim ? j1 : 0u));
        float m0 = (j0 < lim) ? 1.f : 0.f;
        float m1 = (j1 < lim) ? 1.f : 0.f;
        h8 r0 = *reinterpret_cast<const h8*>(sbase + (size_t)s0 * 32 + d8);
        h8 r1 = *reinterpret_cast<const h8*>(sbase + (size_t)s1 * 32 + d8);
        CVT8(accA, accB, r0, m0);
        CVT8(accC, accD, r1, m1);
    }
    for (unsigned j = 64; j < deg; j += 16) {   // overflow: deg > 64 (rare)
        unsigned jj = j + slot;
        bool valid = jj < deg;
        int s = bsrc[start + (valid ? jj : 0u)];
        float m = valid ? 1.f : 0.f;
        h8 r = *reinterpret_cast<const h8*>(sbase + (size_t)s * 32 + d8);
        CVT8(accA, accB, r, m);
    }
    accA.x += accC.x; accA.y += accC.y; accA.z += accC.z; accA.w += accC.w;
    accB.x += accD.x; accB.y += accD.y; accB.z += accD.z; accB.w += accD.w;
#pragma unroll
    for (int off = 32; off >= 4; off >>= 1) {
        accA.x += __shfl_down(accA.x, off); accA.y += __shfl_down(accA.y, off);
        accA.z += __shfl_down(accA.z, off); accA.w += __shfl_down(accA.w, off);
        accB.x += __shfl_down(accB.x, off); accB.y += __shfl_down(accB.y, off);
        accB.z += __shfl_down(accB.z, off); accB.w += __shfl_down(accB.w, off);
    }
    if (slot == 0) {
        float innrm = innorm[node];
        h8 r;
        r[0] = (_Float16)(accA.x * innrm); r[1] = (_Float16)(accA.y * innrm);
        r[2] = (_Float16)(accA.z * innrm); r[3] = (_Float16)(accA.w * innrm);
        r[4] = (_Float16)(accB.x * innrm); r[5] = (_Float16)(accB.y * innrm);
        r[6] = (_Float16)(accB.z * innrm); r[7] = (_Float16)(accB.w * innrm);
        *reinterpret_cast<h8*>(aggh + ((size_t)p * N_NODES + node) * 32 + d8) = r;
    }
}

// ---- node transform via MFMA + fused mean-pool (blocked aggh layout) --------
__global__ __launch_bounds__(256) void k_node(const _Float16* __restrict__ aggh,
                                              const int* __restrict__ gid,
                                              const _Float16* __restrict__ Wt,
                                              const float* __restrict__ b,
                                              float* __restrict__ pooled) {
    __shared__ float red[4][2][DIM];   // 4 KB
    int tid = threadIdx.x;
    int wave = tid >> 6, lane = tid & 63;
    int quad = lane >> 4, m = lane & 15;
    int blockBase = blockIdx.x * NPBM;
    int wbase = blockBase + wave * 32;
    int gfirst = gid[blockBase];
    int gsec = gfirst + 1;

    f4v acc0[8], acc1[8];
#pragma unroll
    for (int t = 0; t < 8; ++t) { acc0[t] = (f4v){0,0,0,0}; acc1[t] = (f4v){0,0,0,0}; }

#pragma unroll
    for (int kk = 0; kk < 4; ++kk) {
        int ko = kk * 32 + quad * 8;
        // blocked layout: K-chunk kk lives at aggh[(kk*N + node)*32 + quad*8]
        h8 a0 = *reinterpret_cast<const h8*>(aggh + ((size_t)kk * N_NODES + wbase + m) * 32 + quad * 8);
        h8 a1 = *reinterpret_cast<const h8*>(aggh + ((size_t)kk * N_NODES + wbase + 16 + m) * 32 + quad * 8);
#pragma unroll
        for (int t = 0; t < 8; ++t) {
            h8 bf = *reinterpret_cast<const h8*>(Wt + (size_t)(t * 16 + m) * DIM + ko);
            acc0[t] = __builtin_amdgcn_mfma_f32_16x16x32_f16(a0, bf, acc0[t], 0, 0, 0);
            acc1[t] = __builtin_amdgcn_mfma_f32_16x16x32_f16(a1, bf, acc1[t], 0, 0, 0);
        }
    }

    int n0 = wbase + quad * 4;
    int n1 = n0 + 16;
    float s0[8], s1[8];
#pragma unroll
    for (int t = 0; t < 8; ++t) {
        float bb = b[t * 16 + m];
        s0[t] = 0.f; s1[t] = 0.f;
#pragma unroll
        for (int r = 0; r < 4; ++r) {
            int node = n0 + r;
            if (node < N_NODES) {
                float h = fmaxf(acc0[t][r] + bb, 0.f);
                int g = gid[node];
                if (g == gfirst)      s0[t] += h;
                else if (g == gsec)   s1[t] += h;
                else atomicAdd(&pooled[(size_t)g * DIM + t * 16 + m], h);
            }
            int node2 = n1 + r;
            if (node2 < N_NODES) {
                float h = fmaxf(acc1[t][r] + bb, 0.f);
                int g = gid[node2];
                if (g == gfirst)      s0[t] += h;
                else if (g == gsec)   s1[t] += h;
                else atomicAdd(&pooled[(size_t)g * DIM + t * 16 + m], h);
            }
        }
        s0[t] += __shfl_down(s0[t], 32);
        s0[t] += __shfl_down(s0[t], 16);
        s1[t] += __shfl_down(s1[t], 32);
        s1[t] += __shfl_down(s1[t], 16);
    }
    if (quad == 0) {
#pragma unroll
        for (int t = 0; t < 8; ++t) {
            red[wave][0][t * 16 + m] = s0[t];
            red[wave][1][t * 16 + m] = s1[t];
        }
    }
    __syncthreads();
    if (tid < DIM) {
        float v0 = red[0][0][tid] + red[1][0][tid] + red[2][0][tid] + red[3][0][tid];
        if (v0 != 0.f) atomicAdd(&pooled[(size_t)gfirst * DIM + tid], v0);
        float v1 = red[0][1][tid] + red[1][1][tid] + red[2][1][tid] + red[3][1][tid];
        if (v1 != 0.f && gsec < N_GRAPHS) atomicAdd(&pooled[(size_t)gsec * DIM + tid], v1);
    }
}

// ---- head: out = (pooled/cnt) @ W_head + b_head -----------------------------
__global__ __launch_bounds__(256) void k_head(const float* __restrict__ pooled,
                                              const int* __restrict__ start,
                                              const float* __restrict__ Wh,
                                              const float* __restrict__ bh,
                                              float* __restrict__ out) {
    int i = blockIdx.x * 256 + threadIdx.x;
    if (i >= N_GRAPHS * N_CLASSES) return;
    int g = i / N_CLASSES, c = i % N_CLASSES;
    const float* pr = pooled + g * DIM;
    float s = 0.f;
#pragma unroll 8
    for (int k = 0; k < DIM; ++k) s += pr[k] * Wh[k * N_CLASSES + c];
    float cntf = fmaxf((float)(start[g + 1] - start[g]), 1.0f);
    out[i] = s / cntf + bh[c];
}

extern "C" void kernel_launch(void* const* d_in, const int* in_sizes, int n_in,
                              void* d_out, int out_size, void* d_ws, size_t ws_size,
                              hipStream_t stream) {
    const float* feat = (const float*)d_in[0];
    const int*   src  = (const int*)d_in[1];
    const int*   dst  = (const int*)d_in[2];
    const int*   gid  = (const int*)d_in[3];
    const float* W    = (const float*)d_in[4];
    const float* b    = (const float*)d_in[5];
    const float* Wh   = (const float*)d_in[6];
    const float* bh   = (const float*)d_in[7];
    float* out = (float*)d_out;

    // ---- workspace layout (4-byte elements) ----
    float*    pooled   = (float*)d_ws;                                  // G*D
    unsigned* indeg    = (unsigned*)(pooled + (size_t)N_GRAPHS * DIM);  // N
    float*    outnorm  = (float*)(indeg + N_NODES);                     // N
    float*    innorm   = outnorm + N_NODES;                             // N
    int*      start    = (int*)(innorm + N_NODES);                      // G+1
    unsigned* row_ptr  = (unsigned*)(start + N_GRAPHS + 1);             // N
    unsigned* blockSums= row_ptr + N_NODES;                             // 256
    unsigned* blockOff = blockSums + 256;                               // 256
    unsigned char* perm= (unsigned char*)(blockOff + 256);              // E bytes
    int*      bsrc     = (int*)(perm + N_EDGES);                        // E
    _Float16* sfeat    = (_Float16*)(bsrc + N_EDGES);                   // N*D halves (blocked)
    _Float16* aggh     = sfeat + (size_t)N_NODES * DIM;                 // N*D halves (blocked)
    _Float16* Wt       = aggh + (size_t)N_NODES * DIM;                  // DIM*DIM halves
    unsigned* Hin      = (unsigned*)(Wt + DIM * DIM);                   // NCHE*LQ
    unsigned* Hout     = Hin + (size_t)NCHE * LQ;                       // NCHE*LQ

    dim3 lh(NCHE, 2);
    k_lhist <<<lh, 256, 0, stream>>>(src, dst, Hin, Hout, perm);
    k_reduce<<<NBR2, 256, 0, stream>>>(Hin, Hout, gid, indeg, outnorm, innorm,
                                       start, row_ptr, blockSums);
    k_scan2 <<<1, 256, 0, stream>>>(blockSums, blockOff, pooled);
    k_prep  <<<PLACE_BLKS + PRES_BLKS + WT_BLKS, 256, 0, stream>>>(
                src, dst, Hin, perm, row_ptr, blockOff, bsrc,
                feat, outnorm, sfeat, W, Wt);
    dim3 gg((N_NODES + 3) / 4, 4);
    k_gather<<<gg, 256, 0, stream>>>(bsrc, row_ptr, blockOff, indeg,
                                     sfeat, innorm, aggh);
    k_node  <<<NBLK_NODE, 256, 0, stream>>>(aggh, gid, Wt, b, pooled);
    k_head  <<<3, 256, 0, stream>>>(pooled, start, Wh, bh, out);
}

// Round 14
// 189.371 us; speedup vs baseline: 1.1844x; 1.1844x over previous
//
#include <hip/hip_runtime.h>

#define N_NODES   50000
#define N_EDGES   800000
#define DIM       128
#define N_GRAPHS  64
#define N_CLASSES 10
#define NCHE      128                  // edge chunks (u8-safe: max count <= deg ~45)
#define CSZ       (N_EDGES / NCHE)     // 6250
#define LQ        (N_NODES / 4)        // 12500 u8-packed words (4 nodes/word)
#define WPB       64                   // words per reduce block (256 nodes)
#define NBR2      ((LQ + WPB - 1) / WPB)   // 196
#define PLACE_BPC ((CSZ + 255) / 256)      // 25
#define PLACE_BLKS (NCHE * PLACE_BPC)      // 3200
#define PRES_BLKS ((N_NODES * DIM / 8 + 255) / 256)  // 3125
#define WT_BLKS   (DIM * DIM / 256)        // 64
#define NPBM      128                  // nodes per block in k_node (MFMA)
#define NBLK_NODE ((N_NODES + NPBM - 1) / NPBM)  // 391

typedef _Float16 h8 __attribute__((ext_vector_type(8)));
typedef float f4v __attribute__((ext_vector_type(4)));

// ---- per-chunk LDS histograms (u8 packed), dst/src phases in parallel blocks
__global__ __launch_bounds__(256) void k_lhist(const int* __restrict__ src,
                                               const int* __restrict__ dst,
                                               unsigned* __restrict__ Hin,
                                               unsigned* __restrict__ Hout,
                                               unsigned char* __restrict__ perm) {
    __shared__ unsigned L[LQ];         // 50 KB
    int c = blockIdx.x, t = threadIdx.x;
    int base = c * CSZ;
    for (int w = t; w < LQ; w += 256) L[w] = 0u;
    __syncthreads();
    if (blockIdx.y == 0) {
        for (int i = t; i < CSZ; i += 256) {
            int d = dst[base + i];
            int sh = (d & 3) * 8;
            unsigned old = atomicAdd(&L[d >> 2], 1u << sh);
            perm[base + i] = (unsigned char)((old >> sh) & 0xffu);
        }
        __syncthreads();
        for (int w = t; w < LQ; w += 256) Hin[(size_t)c * LQ + w] = L[w];
    } else {
        for (int i = t; i < CSZ; i += 256) {
            int s = src[base + i];
            atomicAdd(&L[s >> 2], 1u << ((s & 3) * 8));
        }
        __syncthreads();
        for (int w = t; w < LQ; w += 256) Hout[(size_t)c * LQ + w] = L[w];
    }
}

// ---- reduce: degrees/norms; Hin := per-chunk prefix; boundaries; scan p1 ----
__global__ __launch_bounds__(256) void k_reduce(unsigned* __restrict__ Hin,
                                                const unsigned* __restrict__ Hout,
                                                const int* __restrict__ gid,
                                                unsigned* __restrict__ indeg,
                                                float* __restrict__ outnorm,
                                                float* __restrict__ innorm,
                                                int* __restrict__ start,
                                                unsigned* __restrict__ row_ptr,
                                                unsigned* __restrict__ blockSums) {
    __shared__ unsigned sIn[4][WPB];
    __shared__ unsigned sOut[4][WPB];
    __shared__ unsigned sS[WPB];
    int t = threadIdx.x;
    int wl = t & (WPB - 1);
    int g  = t >> 6;
    int w  = blockIdx.x * WPB + wl;
    unsigned gs = 0, os = 0;
    int c0 = g * (NCHE / 4);
    if (w < LQ) {
        for (int c = c0; c < c0 + NCHE / 4; ++c) {
            gs += Hin[(size_t)c * LQ + w];
            os += Hout[(size_t)c * LQ + w];
        }
    }
    sIn[g][wl] = gs; sOut[g][wl] = os;
    __syncthreads();
    unsigned baseg = 0;
    for (int gg = 0; gg < 4; ++gg) if (gg < g) baseg += sIn[gg][wl];
    if (w < LQ) {
        unsigned running = baseg;
        for (int c = c0; c < c0 + NCHE / 4; ++c) {
            size_t idx = (size_t)c * LQ + w;
            unsigned word = Hin[idx];
            Hin[idx] = running;
            running += word;
        }
    }
    unsigned tot = 0, otot = 0, wtot = 0;
    if (t < WPB) {
        tot  = sIn[0][t] + sIn[1][t] + sIn[2][t] + sIn[3][t];
        otot = sOut[0][t] + sOut[1][t] + sOut[2][t] + sOut[3][t];
        wtot = (tot & 0xffu) + ((tot >> 8) & 0xffu) + ((tot >> 16) & 0xffu) + (tot >> 24);
        sS[t] = wtot;
    }
    __syncthreads();
    for (int off = 1; off < WPB; off <<= 1) {
        unsigned x = (t < WPB && t >= off) ? sS[t - off] : 0u;
        __syncthreads();
        if (t < WPB) sS[t] += x;
        __syncthreads();
    }
    if (t < WPB) {
        int ww = blockIdx.x * WPB + t;
        if (ww < LQ) {
            unsigned r0 = tot & 0xffu, r1 = (tot >> 8) & 0xffu,
                     r2 = (tot >> 16) & 0xffu, r3 = tot >> 24;
            unsigned o0 = otot & 0xffu, o1 = (otot >> 8) & 0xffu,
                     o2 = (otot >> 16) & 0xffu, o3 = otot >> 24;
            unsigned ex = sS[t] - wtot;
            int n = 4 * ww;
            row_ptr[n]     = ex;
            row_ptr[n + 1] = ex + r0;
            row_ptr[n + 2] = ex + r0 + r1;
            row_ptr[n + 3] = ex + r0 + r1 + r2;
            unsigned rr[4] = {r0, r1, r2, r3}, oo[4] = {o0, o1, o2, o3};
#pragma unroll
            for (int j = 0; j < 4; ++j) {
                indeg[n + j]   = rr[j];
                innorm[n + j]  = rsqrtf(fmaxf((float)rr[j], 1.0f));
                outnorm[n + j] = rsqrtf(fmaxf((float)oo[j], 1.0f));
                int i = n + j;
                int gq = gid[i];
                if (i == 0) {
                    for (int x2 = 0; x2 <= gq; ++x2) start[x2] = 0;
                } else {
                    int gp = gid[i - 1];
                    if (gp != gq)
                        for (int x2 = gp + 1; x2 <= gq; ++x2) start[x2] = i;
                }
                if (i == N_NODES - 1)
                    for (int x2 = gq + 1; x2 <= N_GRAPHS; ++x2) start[x2] = N_NODES;
            }
        }
        if (t == WPB - 1) blockSums[blockIdx.x] = sS[WPB - 1];
    }
}

// ---- scan pass 2 + pooled zeroing (replaces the memset dispatch) ------------
__global__ __launch_bounds__(256) void k_scan2(unsigned* __restrict__ blockSums,
                                               unsigned* __restrict__ blockOff,
                                               float* __restrict__ pooled) {
    __shared__ unsigned s[256];
    int t = threadIdx.x;
    unsigned val = (t < NBR2) ? blockSums[t] : 0u;
    s[t] = val;
    __syncthreads();
    for (int off = 1; off < 256; off <<= 1) {
        unsigned x = (t >= off) ? s[t - off] : 0u;
        __syncthreads();
        s[t] += x;
        __syncthreads();
    }
    if (t < NBR2) blockOff[t] = s[t] - val;
    float4 z = {0.f, 0.f, 0.f, 0.f};
    for (int i = t; i < N_GRAPHS * DIM / 4; i += 256)
        reinterpret_cast<float4*>(pooled)[i] = z;
}

// ---- fused: CSR place + fp16 prescale + W^T fp16 build ----------------------
__global__ __launch_bounds__(256) void k_prep(const int* __restrict__ src,
                                              const int* __restrict__ dst,
                                              const unsigned* __restrict__ Hin,
                                              const unsigned char* __restrict__ perm,
                                              const unsigned* __restrict__ row_ptr,
                                              const unsigned* __restrict__ blockOff,
                                              int* __restrict__ bsrc,
                                              const float* __restrict__ feat,
                                              const float* __restrict__ outnorm,
                                              _Float16* __restrict__ sfeat,
                                              const float* __restrict__ W,
                                              _Float16* __restrict__ Wt) {
    int t = threadIdx.x;
    int blk = blockIdx.x;
    if (blk < PLACE_BLKS) {
        int c = blk / PLACE_BPC;
        int i = (blk % PLACE_BPC) * 256 + t;
        if (i < CSZ) {
            int e = c * CSZ + i;
            int d = dst[e];
            int sh = (d & 3) * 8;
            unsigned pre = (Hin[(size_t)c * LQ + (d >> 2)] >> sh) & 0xffu;
            unsigned pos = row_ptr[d] + blockOff[d >> 8] + pre + perm[e];
            bsrc[pos] = src[e];
        }
    } else if (blk < PLACE_BLKS + PRES_BLKS) {
        int i = (blk - PLACE_BLKS) * 256 + t;
        if (i < N_NODES * DIM / 8) {
            int n = i >> 4;
            int d = (i & 15) << 3;
            float nrm = outnorm[n];
            const float4* p = reinterpret_cast<const float4*>(feat + (size_t)n * DIM + d);
            float4 a = p[0], q = p[1];
            h8 r;
            r[0] = (_Float16)(a.x * nrm); r[1] = (_Float16)(a.y * nrm);
            r[2] = (_Float16)(a.z * nrm); r[3] = (_Float16)(a.w * nrm);
            r[4] = (_Float16)(q.x * nrm); r[5] = (_Float16)(q.y * nrm);
            r[6] = (_Float16)(q.z * nrm); r[7] = (_Float16)(q.w * nrm);
            *reinterpret_cast<h8*>(sfeat + (size_t)n * DIM + d) = r;
        }
    } else {
        int i = (blk - PLACE_BLKS - PRES_BLKS) * 256 + t;  // i < DIM*DIM
        int n = i >> 7, k = i & 127;
        Wt[n * DIM + k] = (_Float16)W[k * DIM + n];
    }
}

#define CVT8(ACC_A, ACC_B, R, M) \
    ACC_A.x += (M) * (float)R[0]; ACC_A.y += (M) * (float)R[1]; \
    ACC_A.z += (M) * (float)R[2]; ACC_A.w += (M) * (float)R[3]; \
    ACC_B.x += (M) * (float)R[4]; ACC_B.y += (M) * (float)R[5]; \
    ACC_B.z += (M) * (float)R[6]; ACC_B.w += (M) * (float)R[7];

// ---- gather-sum over fp16 prescaled rows; 4 rows in flight per iteration ----
__global__ __launch_bounds__(256) void k_gather(const int* __restrict__ bsrc,
                                                const unsigned* __restrict__ row_ptr,
                                                const unsigned* __restrict__ blockOff,
                                                const unsigned* __restrict__ indeg,
                                                const _Float16* __restrict__ sfeat,
                                                const float* __restrict__ innorm,
                                                _Float16* __restrict__ aggh) {
    int tid = threadIdx.x;
    int wave = tid >> 6;
    int lane = tid & 63;
    int node = blockIdx.x * 4 + wave;
    if (node >= N_NODES) return;
    unsigned start = row_ptr[node] + blockOff[node >> 8];
    unsigned deg   = indeg[node];
    unsigned lim   = deg < 64u ? deg : 64u;
    int qtr = lane >> 4;
    int d8  = (lane & 15) << 3;
    int sIdx = 0;
    if ((unsigned)lane < lim) sIdx = bsrc[start + lane];
    float4 accA = {0,0,0,0}, accB = {0,0,0,0};
    float4 accC = {0,0,0,0}, accD = {0,0,0,0};
    for (unsigned j = 0; j < lim; j += 16) {
        unsigned j0 = j + qtr, j1 = j + 4 + qtr, j2 = j + 8 + qtr, j3 = j + 12 + qtr;
        int s0 = __shfl(sIdx, (int)(j0 < lim ? j0 : 0u));
        int s1 = __shfl(sIdx, (int)(j1 < lim ? j1 : 0u));
        int s2 = __shfl(sIdx, (int)(j2 < lim ? j2 : 0u));
        int s3 = __shfl(sIdx, (int)(j3 < lim ? j3 : 0u));
        float m0 = (j0 < lim) ? 1.f : 0.f;
        float m1 = (j1 < lim) ? 1.f : 0.f;
        float m2 = (j2 < lim) ? 1.f : 0.f;
        float m3 = (j3 < lim) ? 1.f : 0.f;
        h8 r0 = *reinterpret_cast<const h8*>(sfeat + (size_t)s0 * DIM + d8);
        h8 r1 = *reinterpret_cast<const h8*>(sfeat + (size_t)s1 * DIM + d8);
        h8 r2 = *reinterpret_cast<const h8*>(sfeat + (size_t)s2 * DIM + d8);
        h8 r3 = *reinterpret_cast<const h8*>(sfeat + (size_t)s3 * DIM + d8);
        CVT8(accA, accB, r0, m0);
        CVT8(accC, accD, r1, m1);
        CVT8(accA, accB, r2, m2);
        CVT8(accC, accD, r3, m3);
    }
    for (unsigned j = 64; j < deg; j += 4) {   // overflow: deg > 64
        unsigned jj = j + qtr;
        bool valid = jj < deg;
        int s = bsrc[start + (valid ? jj : 0u)];
        float m = valid ? 1.f : 0.f;
        h8 r = *reinterpret_cast<const h8*>(sfeat + (size_t)s * DIM + d8);
        CVT8(accA, accB, r, m);
    }
    accA.x += accC.x; accA.y += accC.y; accA.z += accC.z; accA.w += accC.w;
    accB.x += accD.x; accB.y += accD.y; accB.z += accD.z; accB.w += accD.w;
    accA.x += __shfl_down(accA.x, 32); accA.y += __shfl_down(accA.y, 32);
    accA.z += __shfl_down(accA.z, 32); accA.w += __shfl_down(accA.w, 32);
    accB.x += __shfl_down(accB.x, 32); accB.y += __shfl_down(accB.y, 32);
    accB.z += __shfl_down(accB.z, 32); accB.w += __shfl_down(accB.w, 32);
    accA.x += __shfl_down(accA.x, 16); accA.y += __shfl_down(accA.y, 16);
    accA.z += __shfl_down(accA.z, 16); accA.w += __shfl_down(accA.w, 16);
    accB.x += __shfl_down(accB.x, 16); accB.y += __shfl_down(accB.y, 16);
    accB.z += __shfl_down(accB.z, 16); accB.w += __shfl_down(accB.w, 16);
    if (qtr == 0) {
        float innrm = innorm[node];
        h8 r;
        r[0] = (_Float16)(accA.x * innrm); r[1] = (_Float16)(accA.y * innrm);
        r[2] = (_Float16)(accA.z * innrm); r[3] = (_Float16)(accA.w * innrm);
        r[4] = (_Float16)(accB.x * innrm); r[5] = (_Float16)(accB.y * innrm);
        r[6] = (_Float16)(accB.z * innrm); r[7] = (_Float16)(accB.w * innrm);
        *reinterpret_cast<h8*>(aggh + (size_t)node * DIM + d8) = r;
    }
}

// ---- node transform via MFMA + fused mean-pool ------------------------------
__global__ __launch_bounds__(256) void k_node(const _Float16* __restrict__ aggh,
                                              const int* __restrict__ gid,
                                              const _Float16* __restrict__ Wt,
                                              const float* __restrict__ b,
                                              float* __restrict__ pooled) {
    __shared__ float red[4][2][DIM];   // 4 KB
    int tid = threadIdx.x;
    int wave = tid >> 6, lane = tid & 63;
    int quad = lane >> 4, m = lane & 15;
    int blockBase = blockIdx.x * NPBM;
    int wbase = blockBase + wave * 32;
    int gfirst = gid[blockBase];
    int gsec = gfirst + 1;

    f4v acc0[8], acc1[8];
#pragma unroll
    for (int t = 0; t < 8; ++t) { acc0[t] = (f4v){0,0,0,0}; acc1[t] = (f4v){0,0,0,0}; }

#pragma unroll
    for (int kk = 0; kk < 4; ++kk) {
        int ko = kk * 32 + quad * 8;
        h8 a0 = *reinterpret_cast<const h8*>(aggh + (size_t)(wbase + m) * DIM + ko);
        h8 a1 = *reinterpret_cast<const h8*>(aggh + (size_t)(wbase + 16 + m) * DIM + ko);
#pragma unroll
        for (int t = 0; t < 8; ++t) {
            h8 bf = *reinterpret_cast<const h8*>(Wt + (size_t)(t * 16 + m) * DIM + ko);
            acc0[t] = __builtin_amdgcn_mfma_f32_16x16x32_f16(a0, bf, acc0[t], 0, 0, 0);
            acc1[t] = __builtin_amdgcn_mfma_f32_16x16x32_f16(a1, bf, acc1[t], 0, 0, 0);
        }
    }

    int n0 = wbase + quad * 4;
    int n1 = n0 + 16;
    float s0[8], s1[8];
#pragma unroll
    for (int t = 0; t < 8; ++t) {
        float bb = b[t * 16 + m];
        s0[t] = 0.f; s1[t] = 0.f;
#pragma unroll
        for (int r = 0; r < 4; ++r) {
            int node = n0 + r;
            if (node < N_NODES) {
                float h = fmaxf(acc0[t][r] + bb, 0.f);
                int g = gid[node];
                if (g == gfirst)      s0[t] += h;
                else if (g == gsec)   s1[t] += h;
                else atomicAdd(&pooled[(size_t)g * DIM + t * 16 + m], h);
            }
            int node2 = n1 + r;
            if (node2 < N_NODES) {
                float h = fmaxf(acc1[t][r] + bb, 0.f);
                int g = gid[node2];
                if (g == gfirst)      s0[t] += h;
                else if (g == gsec)   s1[t] += h;
                else atomicAdd(&pooled[(size_t)g * DIM + t * 16 + m], h);
            }
        }
        s0[t] += __shfl_down(s0[t], 32);
        s0[t] += __shfl_down(s0[t], 16);
        s1[t] += __shfl_down(s1[t], 32);
        s1[t] += __shfl_down(s1[t], 16);
    }
    if (quad == 0) {
#pragma unroll
        for (int t = 0; t < 8; ++t) {
            red[wave][0][t * 16 + m] = s0[t];
            red[wave][1][t * 16 + m] = s1[t];
        }
    }
    __syncthreads();
    if (tid < DIM) {
        float v0 = red[0][0][tid] + red[1][0][tid] + red[2][0][tid] + red[3][0][tid];
        if (v0 != 0.f) atomicAdd(&pooled[(size_t)gfirst * DIM + tid], v0);
        float v1 = red[0][1][tid] + red[1][1][tid] + red[2][1][tid] + red[3][1][tid];
        if (v1 != 0.f && gsec < N_GRAPHS) atomicAdd(&pooled[(size_t)gsec * DIM + tid], v1);
    }
}

// ---- head: out = (pooled/cnt) @ W_head + b_head -----------------------------
__global__ __launch_bounds__(256) void k_head(const float* __restrict__ pooled,
                                              const int* __restrict__ start,
                                              const float* __restrict__ Wh,
                                              const float* __restrict__ bh,
                                              float* __restrict__ out) {
    int i = blockIdx.x * 256 + threadIdx.x;
    if (i >= N_GRAPHS * N_CLASSES) return;
    int g = i / N_CLASSES, c = i % N_CLASSES;
    const float* pr = pooled + g * DIM;
    float s = 0.f;
#pragma unroll 8
    for (int k = 0; k < DIM; ++k) s += pr[k] * Wh[k * N_CLASSES + c];
    float cntf = fmaxf((float)(start[g + 1] - start[g]), 1.0f);
    out[i] = s / cntf + bh[c];
}

extern "C" void kernel_launch(void* const* d_in, const int* in_sizes, int n_in,
                              void* d_out, int out_size, void* d_ws, size_t ws_size,
                              hipStream_t stream) {
    const float* feat = (const float*)d_in[0];
    const int*   src  = (const int*)d_in[1];
    const int*   dst  = (const int*)d_in[2];
    const int*   gid  = (const int*)d_in[3];
    const float* W    = (const float*)d_in[4];
    const float* b    = (const float*)d_in[5];
    const float* Wh   = (const float*)d_in[6];
    const float* bh   = (const float*)d_in[7];
    float* out = (float*)d_out;

    // ---- workspace layout (4-byte elements) ----
    float*    pooled   = (float*)d_ws;                                  // G*D
    unsigned* indeg    = (unsigned*)(pooled + (size_t)N_GRAPHS * DIM);  // N
    float*    outnorm  = (float*)(indeg + N_NODES);                     // N
    float*    innorm   = outnorm + N_NODES;                             // N
    int*      start    = (int*)(innorm + N_NODES);                      // G+1
    unsigned* row_ptr  = (unsigned*)(start + N_GRAPHS + 1);             // N
    unsigned* blockSums= row_ptr + N_NODES;                             // 256
    unsigned* blockOff = blockSums + 256;                               // 256
    unsigned char* perm= (unsigned char*)(blockOff + 256);              // E bytes
    int*      bsrc     = (int*)(perm + N_EDGES);                        // E
    _Float16* sfeat    = (_Float16*)(bsrc + N_EDGES);                   // N*D halves
    _Float16* aggh     = sfeat + (size_t)N_NODES * DIM;                 // N*D halves
    _Float16* Wt       = aggh + (size_t)N_NODES * DIM;                  // DIM*DIM halves
    unsigned* Hin      = (unsigned*)(Wt + DIM * DIM);                   // NCHE*LQ
    unsigned* Hout     = Hin + (size_t)NCHE * LQ;                       // NCHE*LQ

    dim3 lh(NCHE, 2);
    k_lhist <<<lh, 256, 0, stream>>>(src, dst, Hin, Hout, perm);
    k_reduce<<<NBR2, 256, 0, stream>>>(Hin, Hout, gid, indeg, outnorm, innorm,
                                       start, row_ptr, blockSums);
    k_scan2 <<<1, 256, 0, stream>>>(blockSums, blockOff, pooled);
    k_prep  <<<PLACE_BLKS + PRES_BLKS + WT_BLKS, 256, 0, stream>>>(
                src, dst, Hin, perm, row_ptr, blockOff, bsrc,
                feat, outnorm, sfeat, W, Wt);
    k_gather<<<(N_NODES + 3) / 4, 256, 0, stream>>>(bsrc, row_ptr, blockOff, indeg,
                                                    sfeat, innorm, aggh);
    k_node  <<<NBLK_NODE, 256, 0, stream>>>(aggh, gid, Wt, b, pooled);
    k_head  <<<3, 256, 0, stream>>>(pooled, start, Wh, bh, out);
}

// Round 15
// 181.164 us; speedup vs baseline: 1.2380x; 1.0453x over previous
//
#include <hip/hip_runtime.h>

#define N_NODES   50000
#define N_EDGES   800000
#define DIM       128
#define N_GRAPHS  64
#define N_CLASSES 10
#define NCHE      64                   // edge chunks (u8-safe: per-chunk count <= deg ~50)
#define CSZ       (N_EDGES / NCHE)     // 12500
#define LQ        (N_NODES / 4)        // 12500 u8-packed words (4 nodes/word)
#define WPB       64                   // words per reduce block (256 nodes)
#define NBR2      ((LQ + WPB - 1) / WPB)   // 196
#define PLACE_BPC ((CSZ + 255) / 256)      // 49
#define PLACE_BLKS (NCHE * PLACE_BPC)      // 3136
#define PRES_BLKS ((N_NODES * DIM / 8 + 255) / 256)  // 3125
#define WT_BLKS   (DIM * DIM / 256)        // 64
#define NPBM      128                  // nodes per block in k_node (MFMA)
#define NBLK_NODE ((N_NODES + NPBM - 1) / NPBM)  // 391

typedef _Float16 h8 __attribute__((ext_vector_type(8)));
typedef float f4v __attribute__((ext_vector_type(4)));

// ---- per-chunk LDS histograms (u8 packed), dst/src phases in parallel blocks
__global__ __launch_bounds__(256) void k_lhist(const int* __restrict__ src,
                                               const int* __restrict__ dst,
                                               unsigned* __restrict__ Hin,
                                               unsigned* __restrict__ Hout,
                                               unsigned char* __restrict__ perm) {
    __shared__ unsigned L[LQ];         // 50 KB
    int c = blockIdx.x, t = threadIdx.x;
    int base = c * CSZ;
    for (int w = t; w < LQ; w += 256) L[w] = 0u;
    __syncthreads();
    if (blockIdx.y == 0) {
        for (int i = t; i < CSZ; i += 256) {
            int d = dst[base + i];
            int sh = (d & 3) * 8;
            unsigned old = atomicAdd(&L[d >> 2], 1u << sh);
            perm[base + i] = (unsigned char)((old >> sh) & 0xffu);
        }
        __syncthreads();
        for (int w = t; w < LQ; w += 256) Hin[(size_t)c * LQ + w] = L[w];
    } else {
        for (int i = t; i < CSZ; i += 256) {
            int s = src[base + i];
            atomicAdd(&L[s >> 2], 1u << ((s & 3) * 8));
        }
        __syncthreads();
        for (int w = t; w < LQ; w += 256) Hout[(size_t)c * LQ + w] = L[w];
    }
}

// ---- reduce: degrees/norms; Hin := per-chunk prefix; boundaries; scan p1 ----
__global__ __launch_bounds__(256) void k_reduce(unsigned* __restrict__ Hin,
                                                const unsigned* __restrict__ Hout,
                                                const int* __restrict__ gid,
                                                unsigned* __restrict__ indeg,
                                                float* __restrict__ outnorm,
                                                float* __restrict__ innorm,
                                                int* __restrict__ start,
                                                unsigned* __restrict__ row_ptr,
                                                unsigned* __restrict__ blockSums) {
    __shared__ unsigned sIn[4][WPB];
    __shared__ unsigned sOut[4][WPB];
    __shared__ unsigned sS[WPB];
    int t = threadIdx.x;
    int wl = t & (WPB - 1);
    int g  = t >> 6;
    int w  = blockIdx.x * WPB + wl;
    unsigned gs = 0, os = 0;
    int c0 = g * (NCHE / 4);
    if (w < LQ) {
        for (int c = c0; c < c0 + NCHE / 4; ++c) {
            gs += Hin[(size_t)c * LQ + w];     // u8 packed adds: no carry (deg ~50)
            os += Hout[(size_t)c * LQ + w];
        }
    }
    sIn[g][wl] = gs; sOut[g][wl] = os;
    __syncthreads();
    unsigned baseg = 0;
    for (int gg = 0; gg < 4; ++gg) if (gg < g) baseg += sIn[gg][wl];
    if (w < LQ) {
        unsigned running = baseg;
        for (int c = c0; c < c0 + NCHE / 4; ++c) {
            size_t idx = (size_t)c * LQ + w;
            unsigned word = Hin[idx];
            Hin[idx] = running;
            running += word;
        }
    }
    unsigned tot = 0, otot = 0, wtot = 0;
    if (t < WPB) {
        tot  = sIn[0][t] + sIn[1][t] + sIn[2][t] + sIn[3][t];
        otot = sOut[0][t] + sOut[1][t] + sOut[2][t] + sOut[3][t];
        wtot = (tot & 0xffu) + ((tot >> 8) & 0xffu) + ((tot >> 16) & 0xffu) + (tot >> 24);
        sS[t] = wtot;
    }
    __syncthreads();
    for (int off = 1; off < WPB; off <<= 1) {
        unsigned x = (t < WPB && t >= off) ? sS[t - off] : 0u;
        __syncthreads();
        if (t < WPB) sS[t] += x;
        __syncthreads();
    }
    if (t < WPB) {
        int ww = blockIdx.x * WPB + t;
        if (ww < LQ) {
            unsigned r0 = tot & 0xffu, r1 = (tot >> 8) & 0xffu,
                     r2 = (tot >> 16) & 0xffu, r3 = tot >> 24;
            unsigned o0 = otot & 0xffu, o1 = (otot >> 8) & 0xffu,
                     o2 = (otot >> 16) & 0xffu, o3 = otot >> 24;
            unsigned ex = sS[t] - wtot;
            int n = 4 * ww;
            row_ptr[n]     = ex;
            row_ptr[n + 1] = ex + r0;
            row_ptr[n + 2] = ex + r0 + r1;
            row_ptr[n + 3] = ex + r0 + r1 + r2;
            unsigned rr[4] = {r0, r1, r2, r3}, oo[4] = {o0, o1, o2, o3};
#pragma unroll
            for (int j = 0; j < 4; ++j) {
                indeg[n + j]   = rr[j];
                innorm[n + j]  = rsqrtf(fmaxf((float)rr[j], 1.0f));
                outnorm[n + j] = rsqrtf(fmaxf((float)oo[j], 1.0f));
                int i = n + j;
                int gq = gid[i];
                if (i == 0) {
                    for (int x2 = 0; x2 <= gq; ++x2) start[x2] = 0;
                } else {
                    int gp = gid[i - 1];
                    if (gp != gq)
                        for (int x2 = gp + 1; x2 <= gq; ++x2) start[x2] = i;
                }
                if (i == N_NODES - 1)
                    for (int x2 = gq + 1; x2 <= N_GRAPHS; ++x2) start[x2] = N_NODES;
            }
        }
        if (t == WPB - 1) blockSums[blockIdx.x] = sS[WPB - 1];
    }
}

// ---- scan pass 2 + pooled zeroing (replaces the memset dispatch) ------------
__global__ __launch_bounds__(256) void k_scan2(unsigned* __restrict__ blockSums,
                                               unsigned* __restrict__ blockOff,
                                               float* __restrict__ pooled) {
    __shared__ unsigned s[256];
    int t = threadIdx.x;
    unsigned val = (t < NBR2) ? blockSums[t] : 0u;
    s[t] = val;
    __syncthreads();
    for (int off = 1; off < 256; off <<= 1) {
        unsigned x = (t >= off) ? s[t - off] : 0u;
        __syncthreads();
        s[t] += x;
        __syncthreads();
    }
    if (t < NBR2) blockOff[t] = s[t] - val;
    float4 z = {0.f, 0.f, 0.f, 0.f};
    for (int i = t; i < N_GRAPHS * DIM / 4; i += 256)
        reinterpret_cast<float4*>(pooled)[i] = z;
}

// ---- fused: CSR place (u16 bsrc) + fp16 prescale + W^T fp16 build -----------
__global__ __launch_bounds__(256) void k_prep(const int* __restrict__ src,
                                              const int* __restrict__ dst,
                                              const unsigned* __restrict__ Hin,
                                              const unsigned char* __restrict__ perm,
                                              const unsigned* __restrict__ row_ptr,
                                              const unsigned* __restrict__ blockOff,
                                              unsigned short* __restrict__ bsrc,
                                              const float* __restrict__ feat,
                                              const float* __restrict__ outnorm,
                                              _Float16* __restrict__ sfeat,
                                              const float* __restrict__ W,
                                              _Float16* __restrict__ Wt) {
    int t = threadIdx.x;
    int blk = blockIdx.x;
    if (blk < PLACE_BLKS) {
        int c = blk / PLACE_BPC;
        int i = (blk % PLACE_BPC) * 256 + t;
        if (i < CSZ) {
            int e = c * CSZ + i;
            int d = dst[e];
            int sh = (d & 3) * 8;
            unsigned pre = (Hin[(size_t)c * LQ + (d >> 2)] >> sh) & 0xffu;
            unsigned pos = row_ptr[d] + blockOff[d >> 8] + pre + perm[e];
            bsrc[pos] = (unsigned short)src[e];
        }
    } else if (blk < PLACE_BLKS + PRES_BLKS) {
        int i = (blk - PLACE_BLKS) * 256 + t;
        if (i < N_NODES * DIM / 8) {
            int n = i >> 4;
            int d = (i & 15) << 3;
            float nrm = outnorm[n];
            const float4* p = reinterpret_cast<const float4*>(feat + (size_t)n * DIM + d);
            float4 a = p[0], q = p[1];
            h8 r;
            r[0] = (_Float16)(a.x * nrm); r[1] = (_Float16)(a.y * nrm);
            r[2] = (_Float16)(a.z * nrm); r[3] = (_Float16)(a.w * nrm);
            r[4] = (_Float16)(q.x * nrm); r[5] = (_Float16)(q.y * nrm);
            r[6] = (_Float16)(q.z * nrm); r[7] = (_Float16)(q.w * nrm);
            *reinterpret_cast<h8*>(sfeat + (size_t)n * DIM + d) = r;
        }
    } else {
        int i = (blk - PLACE_BLKS - PRES_BLKS) * 256 + t;  // i < DIM*DIM
        int n = i >> 7, k = i & 127;
        Wt[n * DIM + k] = (_Float16)W[k * DIM + n];
    }
}

#define CVT8(ACC_A, ACC_B, R, M) \
    ACC_A.x += (M) * (float)R[0]; ACC_A.y += (M) * (float)R[1]; \
    ACC_A.z += (M) * (float)R[2]; ACC_A.w += (M) * (float)R[3]; \
    ACC_B.x += (M) * (float)R[4]; ACC_B.y += (M) * (float)R[5]; \
    ACC_B.z += (M) * (float)R[6]; ACC_B.w += (M) * (float)R[7];

// ---- gather-sum over fp16 prescaled rows; 4 rows in flight per iteration ----
__global__ __launch_bounds__(256) void k_gather(const unsigned short* __restrict__ bsrc,
                                                const unsigned* __restrict__ row_ptr,
                                                const unsigned* __restrict__ blockOff,
                                                const unsigned* __restrict__ indeg,
                                                const _Float16* __restrict__ sfeat,
                                                const float* __restrict__ innorm,
                                                _Float16* __restrict__ aggh) {
    int tid = threadIdx.x;
    int wave = tid >> 6;
    int lane = tid & 63;
    int node = blockIdx.x * 4 + wave;
    if (node >= N_NODES) return;
    unsigned start = row_ptr[node] + blockOff[node >> 8];
    unsigned deg   = indeg[node];
    unsigned lim   = deg < 64u ? deg : 64u;
    int qtr = lane >> 4;
    int d8  = (lane & 15) << 3;
    int sIdx = 0;
    if ((unsigned)lane < lim) sIdx = bsrc[start + lane];
    float4 accA = {0,0,0,0}, accB = {0,0,0,0};
    float4 accC = {0,0,0,0}, accD = {0,0,0,0};
    for (unsigned j = 0; j < lim; j += 16) {
        unsigned j0 = j + qtr, j1 = j + 4 + qtr, j2 = j + 8 + qtr, j3 = j + 12 + qtr;
        int s0 = __shfl(sIdx, (int)(j0 < lim ? j0 : 0u));
        int s1 = __shfl(sIdx, (int)(j1 < lim ? j1 : 0u));
        int s2 = __shfl(sIdx, (int)(j2 < lim ? j2 : 0u));
        int s3 = __shfl(sIdx, (int)(j3 < lim ? j3 : 0u));
        float m0 = (j0 < lim) ? 1.f : 0.f;
        float m1 = (j1 < lim) ? 1.f : 0.f;
        float m2 = (j2 < lim) ? 1.f : 0.f;
        float m3 = (j3 < lim) ? 1.f : 0.f;
        h8 r0 = *reinterpret_cast<const h8*>(sfeat + (size_t)s0 * DIM + d8);
        h8 r1 = *reinterpret_cast<const h8*>(sfeat + (size_t)s1 * DIM + d8);
        h8 r2 = *reinterpret_cast<const h8*>(sfeat + (size_t)s2 * DIM + d8);
        h8 r3 = *reinterpret_cast<const h8*>(sfeat + (size_t)s3 * DIM + d8);
        CVT8(accA, accB, r0, m0);
        CVT8(accC, accD, r1, m1);
        CVT8(accA, accB, r2, m2);
        CVT8(accC, accD, r3, m3);
    }
    for (unsigned j = 64; j < deg; j += 4) {   // overflow: deg > 64 (rare)
        unsigned jj = j + qtr;
        bool valid = jj < deg;
        int s = bsrc[start + (valid ? jj : 0u)];
        float m = valid ? 1.f : 0.f;
        h8 r = *reinterpret_cast<const h8*>(sfeat + (size_t)s * DIM + d8);
        CVT8(accA, accB, r, m);
    }
    accA.x += accC.x; accA.y += accC.y; accA.z += accC.z; accA.w += accC.w;
    accB.x += accD.x; accB.y += accD.y; accB.z += accD.z; accB.w += accD.w;
    accA.x += __shfl_down(accA.x, 32); accA.y += __shfl_down(accA.y, 32);
    accA.z += __shfl_down(accA.z, 32); accA.w += __shfl_down(accA.w, 32);
    accB.x += __shfl_down(accB.x, 32); accB.y += __shfl_down(accB.y, 32);
    accB.z += __shfl_down(accB.z, 32); accB.w += __shfl_down(accB.w, 32);
    accA.x += __shfl_down(accA.x, 16); accA.y += __shfl_down(accA.y, 16);
    accA.z += __shfl_down(accA.z, 16); accA.w += __shfl_down(accA.w, 16);
    accB.x += __shfl_down(accB.x, 16); accB.y += __shfl_down(accB.y, 16);
    accB.z += __shfl_down(accB.z, 16); accB.w += __shfl_down(accB.w, 16);
    if (qtr == 0) {
        float innrm = innorm[node];
        h8 r;
        r[0] = (_Float16)(accA.x * innrm); r[1] = (_Float16)(accA.y * innrm);
        r[2] = (_Float16)(accA.z * innrm); r[3] = (_Float16)(accA.w * innrm);
        r[4] = (_Float16)(accB.x * innrm); r[5] = (_Float16)(accB.y * innrm);
        r[6] = (_Float16)(accB.z * innrm); r[7] = (_Float16)(accB.w * innrm);
        *reinterpret_cast<h8*>(aggh + (size_t)node * DIM + d8) = r;
    }
}

// ---- node transform via MFMA + fused mean-pool ------------------------------
__global__ __launch_bounds__(256) void k_node(const _Float16* __restrict__ aggh,
                                              const int* __restrict__ gid,
                                              const _Float16* __restrict__ Wt,
                                              const float* __restrict__ b,
                                              float* __restrict__ pooled) {
    __shared__ float red[4][2][DIM];   // 4 KB
    int tid = threadIdx.x;
    int wave = tid >> 6, lane = tid & 63;
    int quad = lane >> 4, m = lane & 15;
    int blockBase = blockIdx.x * NPBM;
    int wbase = blockBase + wave * 32;
    int gfirst = gid[blockBase];
    int gsec = gfirst + 1;

    f4v acc0[8], acc1[8];
#pragma unroll
    for (int t = 0; t < 8; ++t) { acc0[t] = (f4v){0,0,0,0}; acc1[t] = (f4v){0,0,0,0}; }

#pragma unroll
    for (int kk = 0; kk < 4; ++kk) {
        int ko = kk * 32 + quad * 8;
        h8 a0 = *reinterpret_cast<const h8*>(aggh + (size_t)(wbase + m) * DIM + ko);
        h8 a1 = *reinterpret_cast<const h8*>(aggh + (size_t)(wbase + 16 + m) * DIM + ko);
#pragma unroll
        for (int t = 0; t < 8; ++t) {
            h8 bf = *reinterpret_cast<const h8*>(Wt + (size_t)(t * 16 + m) * DIM + ko);
            acc0[t] = __builtin_amdgcn_mfma_f32_16x16x32_f16(a0, bf, acc0[t], 0, 0, 0);
            acc1[t] = __builtin_amdgcn_mfma_f32_16x16x32_f16(a1, bf, acc1[t], 0, 0, 0);
        }
    }

    int n0 = wbase + quad * 4;
    int n1 = n0 + 16;
    float s0[8], s1[8];
#pragma unroll
    for (int t = 0; t < 8; ++t) {
        float bb = b[t * 16 + m];
        s0[t] = 0.f; s1[t] = 0.f;
#pragma unroll
        for (int r = 0; r < 4; ++r) {
            int node = n0 + r;
            if (node < N_NODES) {
                float h = fmaxf(acc0[t][r] + bb, 0.f);
                int g = gid[node];
                if (g == gfirst)      s0[t] += h;
                else if (g == gsec)   s1[t] += h;
                else atomicAdd(&pooled[(size_t)g * DIM + t * 16 + m], h);
            }
            int node2 = n1 + r;
            if (node2 < N_NODES) {
                float h = fmaxf(acc1[t][r] + bb, 0.f);
                int g = gid[node2];
                if (g == gfirst)      s0[t] += h;
                else if (g == gsec)   s1[t] += h;
                else atomicAdd(&pooled[(size_t)g * DIM + t * 16 + m], h);
            }
        }
        s0[t] += __shfl_down(s0[t], 32);
        s0[t] += __shfl_down(s0[t], 16);
        s1[t] += __shfl_down(s1[t], 32);
        s1[t] += __shfl_down(s1[t], 16);
    }
    if (quad == 0) {
#pragma unroll
        for (int t = 0; t < 8; ++t) {
            red[wave][0][t * 16 + m] = s0[t];
            red[wave][1][t * 16 + m] = s1[t];
        }
    }
    __syncthreads();
    if (tid < DIM) {
        float v0 = red[0][0][tid] + red[1][0][tid] + red[2][0][tid] + red[3][0][tid];
        if (v0 != 0.f) atomicAdd(&pooled[(size_t)gfirst * DIM + tid], v0);
        float v1 = red[0][1][tid] + red[1][1][tid] + red[2][1][tid] + red[3][1][tid];
        if (v1 != 0.f && gsec < N_GRAPHS) atomicAdd(&pooled[(size_t)gsec * DIM + tid], v1);
    }
}

// ---- head: out = (pooled/cnt) @ W_head + b_head -----------------------------
__global__ __launch_bounds__(256) void k_head(const float* __restrict__ pooled,
                                              const int* __restrict__ start,
                                              const float* __restrict__ Wh,
                                              const float* __restrict__ bh,
                                              float* __restrict__ out) {
    int i = blockIdx.x * 256 + threadIdx.x;
    if (i >= N_GRAPHS * N_CLASSES) return;
    int g = i / N_CLASSES, c = i % N_CLASSES;
    const float* pr = pooled + g * DIM;
    float s = 0.f;
#pragma unroll 8
    for (int k = 0; k < DIM; ++k) s += pr[k] * Wh[k * N_CLASSES + c];
    float cntf = fmaxf((float)(start[g + 1] - start[g]), 1.0f);
    out[i] = s / cntf + bh[c];
}

extern "C" void kernel_launch(void* const* d_in, const int* in_sizes, int n_in,
                              void* d_out, int out_size, void* d_ws, size_t ws_size,
                              hipStream_t stream) {
    const float* feat = (const float*)d_in[0];
    const int*   src  = (const int*)d_in[1];
    const int*   dst  = (const int*)d_in[2];
    const int*   gid  = (const int*)d_in[3];
    const float* W    = (const float*)d_in[4];
    const float* b    = (const float*)d_in[5];
    const float* Wh   = (const float*)d_in[6];
    const float* bh   = (const float*)d_in[7];
    float* out = (float*)d_out;

    // ---- workspace layout (4-byte elements; 16B-aligned regions) ----
    float*    pooled   = (float*)d_ws;                                  // G*D
    unsigned* indeg    = (unsigned*)(pooled + (size_t)N_GRAPHS * DIM);  // N
    float*    outnorm  = (float*)(indeg + N_NODES);                     // N
    float*    innorm   = outnorm + N_NODES;                             // N
    int*      start    = (int*)(innorm + N_NODES);                      // G+1 (pad to 128)
    unsigned* row_ptr  = (unsigned*)(start + 128);                      // N
    unsigned* blockSums= row_ptr + N_NODES;                             // 256
    unsigned* blockOff = blockSums + 256;                               // 256
    unsigned char* perm= (unsigned char*)(blockOff + 256);              // E bytes
    unsigned short* bsrc = (unsigned short*)(perm + N_EDGES);           // E u16
    _Float16* sfeat    = (_Float16*)(bsrc + N_EDGES);                   // N*D halves
    _Float16* aggh     = sfeat + (size_t)N_NODES * DIM;                 // N*D halves
    _Float16* Wt       = aggh + (size_t)N_NODES * DIM;                  // DIM*DIM halves
    unsigned* Hin      = (unsigned*)(Wt + DIM * DIM);                   // NCHE*LQ
    unsigned* Hout     = Hin + (size_t)NCHE * LQ;                       // NCHE*LQ

    dim3 lh(NCHE, 2);
    k_lhist <<<lh, 256, 0, stream>>>(src, dst, Hin, Hout, perm);
    k_reduce<<<NBR2, 256, 0, stream>>>(Hin, Hout, gid, indeg, outnorm, innorm,
                                       start, row_ptr, blockSums);
    k_scan2 <<<1, 256, 0, stream>>>(blockSums, blockOff, pooled);
    k_prep  <<<PLACE_BLKS + PRES_BLKS + WT_BLKS, 256, 0, stream>>>(
                src, dst, Hin, perm, row_ptr, blockOff, bsrc,
                feat, outnorm, sfeat, W, Wt);
    k_gather<<<(N_NODES + 3) / 4, 256, 0, stream>>>(bsrc, row_ptr, blockOff, indeg,
                                                    sfeat, innorm, aggh);
    k_node  <<<NBLK_NODE, 256, 0, stream>>>(aggh, gid, Wt, b, pooled);
    k_head  <<<3, 256, 0, stream>>>(pooled, start, Wh, bh, out);
}